// Round 5
// baseline (305.648 us; speedup 1.0000x reference)
//
#include <hip/hip_runtime.h>
#include <hip/hip_bf16.h>

// LSTM: I=32, H=64, O=8, B=4096, T=256, fused single kernel.
// Round 11: round-6 occupancy structure (BR=8, grid=512, 2 blocks/CU,
// permuted-mirror full-M MFMA) + round-10 trans-pipe activations.
//  - Round 10 analysis: per-step wall ~1460cy, busy ~860cy, ~600cy exposed
//    stall (barrier -> ds_read -> MFMA -> exp/rcp chain) with 1 wave/SIMD.
//    Fix = 2 independent blocks/CU: unsynchronized barriers, block A covers
//    block B's latency. Mirror trick (round 6, proven): every lane's
//    acc[g][0..1] are real cells; 2 cells/lane packed f32x2.
//  - Activations: sigmoid = rcp(1+exp2(-x*log2e)), tanh = (e-1)*rcp(e+1)
//    with e = exp2(2x*log2e), input clamped +-10 (round 10, proven).
//  - h bf16 in LDS double buffer, ONE __syncthreads per step; x from global,
//    chunked 8 steps, truncation bf16 pack.

#define T_LEN 256
#define I_SZ  32
#define H_SZ  64
#define O_SZ  8
#define BR    8
#define HS    72   // h row stride in shorts

typedef __attribute__((ext_vector_type(8))) short short8;
typedef __attribute__((ext_vector_type(4))) float f32x4;
typedef __attribute__((ext_vector_type(2))) float f32x2;

static __device__ __forceinline__ unsigned fbits(float f) {
    union { float f; unsigned u; } v; v.f = f; return v.u;
}
// two floats -> packed bf16x2 (truncation): elem0 = lo, elem1 = hi
static __device__ __forceinline__ unsigned pk2t(float lo, float hi) {
    return __builtin_amdgcn_perm(fbits(hi), fbits(lo), 0x07060302u);
}
static __device__ __forceinline__ short f2bf_rne(float f) {   // init-time only
    union { __hip_bfloat16 b; short s; } u;
    u.b = __float2bfloat16(f);
    return u.s;
}

#define LOG2E     1.4426950408889634f
#define TWO_LOG2E 2.8853900817779268f

// sigmoid(x) = rcp(1 + exp2(-x*log2e)); graceful saturation at large |x|.
static __device__ __forceinline__ f32x2 sig2(f32x2 x) {
    float ex = __builtin_amdgcn_exp2f(x.x * (-LOG2E));
    float ey = __builtin_amdgcn_exp2f(x.y * (-LOG2E));
    f32x2 r;
    r.x = __builtin_amdgcn_rcpf(ex + 1.0f);
    r.y = __builtin_amdgcn_rcpf(ey + 1.0f);
    return r;
}
// tanh(x) = (e-1)*rcp(e+1), e = exp2(2x*log2e), x clamped +-10.
static __device__ __forceinline__ f32x2 tanh2(f32x2 x) {
    float cx = __builtin_amdgcn_fmed3f(x.x, -10.0f, 10.0f);
    float cy = __builtin_amdgcn_fmed3f(x.y, -10.0f, 10.0f);
    float ex = __builtin_amdgcn_exp2f(cx * TWO_LOG2E);
    float ey = __builtin_amdgcn_exp2f(cy * TWO_LOG2E);
    f32x2 r;
    r.x = (ex - 1.0f) * __builtin_amdgcn_rcpf(ex + 1.0f);
    r.y = (ey - 1.0f) * __builtin_amdgcn_rcpf(ey + 1.0f);
    return r;
}
static __device__ __forceinline__ f32x2 fma2(f32x2 a, f32x2 b, f32x2 c) {
    return __builtin_elementwise_fma(a, b, c);
}

__global__ __launch_bounds__(256, 2)
void lstm_fused_kernel(const float* __restrict__ x,
                       const float* __restrict__ W_ih,
                       const float* __restrict__ W_hh,
                       const float* __restrict__ b_ih,
                       const float* __restrict__ b_hh,
                       const float* __restrict__ W_fc,
                       const float* __restrict__ b_fc,
                       float* __restrict__ out)
{
    __shared__ short hbuf[2][8][HS];   // h double buffer, bf16, rows 0..7
    __shared__ float Hf[BR][64];

    const int tid  = threadIdx.x;
    const int wave = tid >> 6;
    const int lane = tid & 63;
    const int quad = lane >> 4;
    const int nlow = lane & 15;
    const int jw   = wave * 16 + nlow;   // gate-col this lane's tiles own
    const int b0   = blockIdx.x * BR;

    // Permuted mirror row for A-reads: {0..7, 2,3,2,3, 6,7,6,7}
    const int fr = (nlow < 8) ? nlow : (((nlow & 4) ? 6 : 2) + (nlow & 1));
    // Cell rows this lane owns (uses acc[0],acc[1]): q0->0,1 q1->4,5 q2->2,3 q3->6,7
    const int ra = ((quad & 1) << 2) | (quad & 2);

    // ---- B fragments (weights) once into registers.
    short8 bfrag[4][3];
    f32x4  biasf[4];
    for (int g = 0; g < 4; ++g) {
        const int col = g * 64 + jw;
        {
            const float* wr = W_ih + col * I_SZ + quad * 8;
            short8 f;
            #pragma unroll
            for (int e = 0; e < 8; ++e) f[e] = f2bf_rne(wr[e]);
            bfrag[g][0] = f;
        }
        #pragma unroll
        for (int kt = 1; kt < 3; ++kt) {
            const float* wr = W_hh + col * H_SZ + (kt - 1) * 32 + quad * 8;
            short8 f;
            #pragma unroll
            for (int e = 0; e < 8; ++e) f[e] = f2bf_rne(wr[e]);
            bfrag[g][kt] = f;
        }
        const float bg = b_ih[col] + b_hh[col];
        biasf[g] = (f32x4){bg, bg, bg, bg};
    }

    // ---- zero h buffers (h0 = 0)
    for (int q = tid; q < 2 * 8 * HS; q += 256) ((short*)hbuf)[q] = (short)0;

    // ---- x chunk machinery: lane owns x[b0+fr][t][quad*8 .. +7].
    const float* xb = x + ((size_t)(b0 + fr) * T_LEN) * I_SZ + quad * 8;

    float4 nx[16];                        // next-chunk fp32 (8 steps x 8 floats)
    short8 sc[8];                         // current-chunk bf16 fragments
    #pragma unroll
    for (int s = 0; s < 8; ++s) {
        nx[2*s]   = *(const float4*)(xb + s * I_SZ);
        nx[2*s+1] = *(const float4*)(xb + s * I_SZ + 4);
    }
    #pragma unroll
    for (int s = 0; s < 8; ++s) {
        union { uint4 u; short8 v; } w;
        w.u.x = pk2t(nx[2*s].x,   nx[2*s].y);
        w.u.y = pk2t(nx[2*s].z,   nx[2*s].w);
        w.u.z = pk2t(nx[2*s+1].x, nx[2*s+1].y);
        w.u.w = pk2t(nx[2*s+1].z, nx[2*s+1].w);
        sc[s] = w.v;
    }

    // LDS addresses
    const short* rb[2] = { &hbuf[0][fr][quad * 8], &hbuf[1][fr][quad * 8] };
    short*       wb[2] = { &hbuf[0][ra][jw],       &hbuf[1][ra][jw] };

    f32x2 cc = {0.f, 0.f};
    f32x2 hh = {0.f, 0.f};

    for (int ch = 0; ch < 32; ++ch) {
        #pragma unroll
        for (int tc = 0; tc < 8; ++tc) {
            const int t = ch * 8 + tc;

            __syncthreads();             // h_{t-1} (and at t=0 the zeroing) visible

            // h fragments: A[m][k = 32*kt + quad*8 + e], rows via fr
            const short* hr = rb[t & 1];
            short8 a1 = *(const short8*)(hr);        // h cols  0..31
            short8 a2 = *(const short8*)(hr + 32);   // h cols 32..63

            // issue next chunk's global loads early in the chunk
            if (tc == 0 && ch + 1 < 32) {
                const float* nxt = xb + (t + 8) * I_SZ;
                #pragma unroll
                for (int s = 0; s < 8; ++s) {
                    nx[2*s]   = *(const float4*)(nxt + s * I_SZ);
                    nx[2*s+1] = *(const float4*)(nxt + s * I_SZ + 4);
                }
            }

            const short8 ax = sc[tc];

            f32x4 acc[4];
            #pragma unroll
            for (int g = 0; g < 4; ++g) {
                f32x4 a = __builtin_amdgcn_mfma_f32_16x16x32_bf16(ax, bfrag[g][0], biasf[g], 0, 0, 0);
                a = __builtin_amdgcn_mfma_f32_16x16x32_bf16(a1, bfrag[g][1], a, 0, 0, 0);
                a = __builtin_amdgcn_mfma_f32_16x16x32_bf16(a2, bfrag[g][2], a, 0, 0, 0);
                acc[g] = a;
            }

            // convert next chunk once its loads landed (7 steps of cover)
            if (tc == 7 && ch + 1 < 32) {
                #pragma unroll
                for (int s = 0; s < 8; ++s) {
                    union { uint4 u; short8 v; } w;
                    w.u.x = pk2t(nx[2*s].x,   nx[2*s].y);
                    w.u.y = pk2t(nx[2*s].z,   nx[2*s].w);
                    w.u.z = pk2t(nx[2*s+1].x, nx[2*s+1].y);
                    w.u.w = pk2t(nx[2*s+1].z, nx[2*s+1].w);
                    sc[s] = w.v;
                }
            }

            // ---- dense packed cell update: cells (ra, jw) and (ra+1, jw).
            // Every lane uses acc[g][0..1] thanks to the permuted mirror read.
            f32x2 pI = {acc[0][0], acc[0][1]};
            f32x2 pF = {acc[1][0], acc[1][1]};
            f32x2 pG = {acc[2][0], acc[2][1]};
            f32x2 pO = {acc[3][0], acc[3][1]};

            f32x2 iv = sig2(pI);
            f32x2 fv = sig2(pF);
            f32x2 gv = tanh2(pG);
            f32x2 ov = sig2(pO);
            cc = fma2(fv, cc, iv * gv);
            hh = ov * tanh2(cc);

            short* hw = wb[(t + 1) & 1];
            hw[0]  = (short)((fbits(hh.x) + 0x8000u) >> 16);
            hw[HS] = (short)((fbits(hh.y) + 0x8000u) >> 16);
        }
    }

    // ---- epilogue: out[b0+r][o] = h_T[r] . W_fc[o] + b_fc[o]  (fp32 h)
    Hf[ra][jw]     = hh.x;
    Hf[ra + 1][jw] = hh.y;
    __syncthreads();

    if (tid < BR * O_SZ) {               // 64 threads
        const int r = tid >> 3;
        const int o = tid & 7;
        const float* wf = W_fc + o * H_SZ;
        float acc = b_fc[o];
        #pragma unroll
        for (int jx = 0; jx < H_SZ; ++jx) acc += Hf[r][jx] * wf[jx];
        out[(size_t)(b0 + r) * O_SZ + o] = acc;
    }
}

extern "C" void kernel_launch(void* const* d_in, const int* in_sizes, int n_in,
                              void* d_out, int out_size, void* d_ws, size_t ws_size,
                              hipStream_t stream) {
    const float* x    = (const float*)d_in[0];
    const float* W_ih = (const float*)d_in[1];
    const float* W_hh = (const float*)d_in[2];
    const float* b_ih = (const float*)d_in[3];
    const float* b_hh = (const float*)d_in[4];
    const float* W_fc = (const float*)d_in[5];
    const float* b_fc = (const float*)d_in[6];
    float* out = (float*)d_out;

    const int B = 4096;
    lstm_fused_kernel<<<dim3(B / BR), dim3(256), 0, stream>>>(
        x, W_ih, W_hh, b_ih, b_hh, W_fc, b_fc, out);
}

// Round 6
// 282.009 us; speedup vs baseline: 1.0838x; 1.0838x over previous
//
#include <hip/hip_runtime.h>
#include <hip/hip_bf16.h>

// LSTM: I=32, H=64, O=8, B=4096, T=256, fused single kernel.
// Round 12: round-10 structure (BR=16 full-M, grid 256, 1 blk/CU, proven
// 156us) + activation op-count cut + x-proj software pipeline.
//  - Lesson R11: per-SIMD activation issue is INVARIANT to wave layout
//    (cells/CU fixed); extra blocks only add MFMA + convoy. Attack ops/cell.
//  - Weights/bias pre-scaled by -log2e (i,f,o) / -2log2e (g) at bf16
//    convert: MFMA outputs are exp2-ready, pre-exp muls eliminated.
//  - Combined rcp: iv*gv = (1-eg)*rcp((1+ei)(1+eg)),
//    ov*tanh(cc) = (1-ec)*rcp((1+eo)(1+ec)). 3 rcp/cell instead of 5.
//    Clamps (med3) only on eg/ec args (the inf*0=NaN paths).
//    15V + 8T per cell (was 19V + 10T).
//  - x-projection pipelined: preacc[g] = MFMA(ax_next, Wih, bias) issued
//    during step t as independent filler; post-barrier chain = 2 MFMAs.
//  - No inline asm (R8/9 hazard lesson). Builtins only.

#define T_LEN 256
#define I_SZ  32
#define H_SZ  64
#define O_SZ  8
#define BR    16
#define HS    72   // h row stride in shorts

typedef __attribute__((ext_vector_type(8))) short short8;
typedef __attribute__((ext_vector_type(4))) float f32x4;

static __device__ __forceinline__ unsigned fbits(float f) {
    union { float f; unsigned u; } v; v.f = f; return v.u;
}
// two floats -> packed bf16x2 (truncation): elem0 = lo, elem1 = hi
static __device__ __forceinline__ unsigned pk2t(float lo, float hi) {
    return __builtin_amdgcn_perm(fbits(hi), fbits(lo), 0x07060302u);
}
static __device__ __forceinline__ short f2bf_rne(float f) {   // init-time only
    union { __hip_bfloat16 b; short s; } u;
    u.b = __float2bfloat16(f);
    return u.s;
}
static __device__ __forceinline__ f32x4 rcp4(f32x4 d) {
    f32x4 r;
    r.x = __builtin_amdgcn_rcpf(d.x);
    r.y = __builtin_amdgcn_rcpf(d.y);
    r.z = __builtin_amdgcn_rcpf(d.z);
    r.w = __builtin_amdgcn_rcpf(d.w);
    return r;
}
static __device__ __forceinline__ f32x4 exp2_4(f32x4 m) {
    f32x4 e;
    e.x = __builtin_amdgcn_exp2f(m.x);
    e.y = __builtin_amdgcn_exp2f(m.y);
    e.z = __builtin_amdgcn_exp2f(m.z);
    e.w = __builtin_amdgcn_exp2f(m.w);
    return e;
}
static __device__ __forceinline__ f32x4 clamp4(f32x4 x, float lo, float hi) {
    f32x4 r;
    r.x = __builtin_amdgcn_fmed3f(x.x, lo, hi);
    r.y = __builtin_amdgcn_fmed3f(x.y, lo, hi);
    r.z = __builtin_amdgcn_fmed3f(x.z, lo, hi);
    r.w = __builtin_amdgcn_fmed3f(x.w, lo, hi);
    return r;
}
static __device__ __forceinline__ f32x4 fma4(f32x4 a, f32x4 b, f32x4 c) {
    return __builtin_elementwise_fma(a, b, c);
}

#define LOG2E     1.4426950408889634f
#define TWO_LOG2E 2.8853900817779268f
#define ECLAMP    28.8f   // exp2-domain clamp: tanh saturation at |x|=10

__global__ __launch_bounds__(256, 1)
void lstm_fused_kernel(const float* __restrict__ x,
                       const float* __restrict__ W_ih,
                       const float* __restrict__ W_hh,
                       const float* __restrict__ b_ih,
                       const float* __restrict__ b_hh,
                       const float* __restrict__ W_fc,
                       const float* __restrict__ b_fc,
                       float* __restrict__ out)
{
    __shared__ short hbuf[2][BR][HS];   // h double buffer, bf16, 16 real rows
    __shared__ float Hf[BR][64];

    const int tid   = threadIdx.x;
    const int wave  = tid >> 6;
    const int lane  = tid & 63;
    const int quad  = lane >> 4;
    const int nlow  = lane & 15;
    const int jw    = wave * 16 + nlow;  // hidden col this lane's tiles own
    const int rbase = quad * 4;          // D rows this lane owns (real rows)
    const int b0    = blockIdx.x * BR;

    // ---- B fragments, PRE-SCALED so MFMA emits exp2-ready args.
    // gates 0,1,3 (i,f,o): scale -log2e ; gate 2 (g): scale -2log2e.
    short8 bfrag[4][3];
    f32x4  biasf[4];
    for (int g = 0; g < 4; ++g) {
        const float scale = (g == 2) ? -TWO_LOG2E : -LOG2E;
        const int col = g * 64 + jw;
        {
            const float* wr = W_ih + col * I_SZ + quad * 8;
            short8 f;
            #pragma unroll
            for (int e = 0; e < 8; ++e) f[e] = f2bf_rne(scale * wr[e]);
            bfrag[g][0] = f;
        }
        #pragma unroll
        for (int kt = 1; kt < 3; ++kt) {
            const float* wr = W_hh + col * H_SZ + (kt - 1) * 32 + quad * 8;
            short8 f;
            #pragma unroll
            for (int e = 0; e < 8; ++e) f[e] = f2bf_rne(scale * wr[e]);
            bfrag[g][kt] = f;
        }
        const float bg = scale * (b_ih[col] + b_hh[col]);
        biasf[g] = (f32x4){bg, bg, bg, bg};
    }

    // ---- zero h buffers (h0 = 0)
    for (int q = tid; q < 2 * BR * HS; q += 256) ((short*)hbuf)[q] = (short)0;

    // ---- x machinery: lane owns x[b0+nlow][t][quad*8 .. +7] (A row = nlow).
    const float* xb = x + ((size_t)(b0 + nlow) * T_LEN) * I_SZ + quad * 8;

    float4 nx[16];                        // next-chunk fp32 (8 steps x 8 floats)
    short8 sc[8];                         // current-chunk bf16 fragments
    #pragma unroll
    for (int s = 0; s < 8; ++s) {
        nx[2*s]   = *(const float4*)(xb + s * I_SZ);
        nx[2*s+1] = *(const float4*)(xb + s * I_SZ + 4);
    }
    #pragma unroll
    for (int s = 0; s < 8; ++s) {
        union { uint4 u; short8 v; } w;
        w.u.x = pk2t(nx[2*s].x,   nx[2*s].y);
        w.u.y = pk2t(nx[2*s].z,   nx[2*s].w);
        w.u.z = pk2t(nx[2*s+1].x, nx[2*s+1].y);
        w.u.w = pk2t(nx[2*s+1].z, nx[2*s+1].w);
        sc[s] = w.v;
    }

    // LDS addresses: read A rows by nlow; write own 4 cell rows at col jw.
    const short* rb[2] = { &hbuf[0][nlow][quad * 8], &hbuf[1][nlow][quad * 8] };
    short*       wb[2] = { &hbuf[0][rbase][jw],      &hbuf[1][rbase][jw] };

    f32x4 cc = {0.f, 0.f, 0.f, 0.f};
    f32x4 hh = {0.f, 0.f, 0.f, 0.f};

    // ---- x-projection pipeline: preacc[g] holds MFMA(ax_t, Wih, bias)
    // for the UPCOMING step, computed one step early (independent filler).
    f32x4 preacc[4];
    #pragma unroll
    for (int g = 0; g < 4; ++g)
        preacc[g] = __builtin_amdgcn_mfma_f32_16x16x32_bf16(sc[0], bfrag[g][0], biasf[g], 0, 0, 0);

    for (int ch = 0; ch < 32; ++ch) {
        #pragma unroll
        for (int tc = 0; tc < 8; ++tc) {
            const int t = ch * 8 + tc;

            __syncthreads();             // h_{t-1} (and at t=0 the zeroing) visible

            // h fragments: A[m = nlow][k = 32*kt + quad*8 + e]
            const short* hr = rb[t & 1];
            short8 a1 = *(const short8*)(hr);        // h cols  0..31
            short8 a2 = *(const short8*)(hr + 32);   // h cols 32..63

            // issue next chunk's global loads early in the chunk
            if (tc == 0 && ch + 1 < 32) {
                const float* nxt = xb + (t + 8) * I_SZ;
                #pragma unroll
                for (int s = 0; s < 8; ++s) {
                    nx[2*s]   = *(const float4*)(nxt + s * I_SZ);
                    nx[2*s+1] = *(const float4*)(nxt + s * I_SZ + 4);
                }
            }

            // post-barrier dependent chain: only 2 MFMAs deep (C = preacc).
            f32x4 acc[4];
            #pragma unroll
            for (int g = 0; g < 4; ++g) {
                f32x4 a = __builtin_amdgcn_mfma_f32_16x16x32_bf16(a1, bfrag[g][1], preacc[g], 0, 0, 0);
                a = __builtin_amdgcn_mfma_f32_16x16x32_bf16(a2, bfrag[g][2], a, 0, 0, 0);
                acc[g] = a;
            }

            // convert next chunk once its loads landed (7 steps of cover);
            // must precede preacc computation at tc==7 (it reads sc[0]).
            if (tc == 7 && ch + 1 < 32) {
                #pragma unroll
                for (int s = 0; s < 8; ++s) {
                    union { uint4 u; short8 v; } w;
                    w.u.x = pk2t(nx[2*s].x,   nx[2*s].y);
                    w.u.y = pk2t(nx[2*s].z,   nx[2*s].w);
                    w.u.z = pk2t(nx[2*s+1].x, nx[2*s+1].y);
                    w.u.w = pk2t(nx[2*s+1].z, nx[2*s+1].w);
                    sc[s] = w.v;
                }
            }

            // x-projection for step t+1: independent of h -> pure filler
            // under the activation trans chains. (Last step: harmless junk.)
            const short8 nax = sc[(tc + 1) & 7];
            #pragma unroll
            for (int g = 0; g < 4; ++g)
                preacc[g] = __builtin_amdgcn_mfma_f32_16x16x32_bf16(nax, bfrag[g][0], biasf[g], 0, 0, 0);

            // ---- cell update: 4 cells/lane, exp2-ready gate args.
            // acc[0]=-log2e*i, acc[1]=-log2e*f, acc[2]=-2log2e*g, acc[3]=-log2e*o
            f32x4 ei = exp2_4(acc[0]);
            f32x4 ef = exp2_4(acc[1]);
            f32x4 eg = exp2_4(clamp4(acc[2], -ECLAMP, ECLAMP));
            f32x4 eo = exp2_4(acc[3]);
            f32x4 fv = rcp4(ef + 1.0f);                            // sigmoid(f)
            f32x4 ig = (1.0f - eg) * rcp4((ei + 1.0f) * (eg + 1.0f)); // sig(i)*tanh(g)
            cc = fma4(fv, cc, ig);
            f32x4 ec = exp2_4(clamp4(cc * (-TWO_LOG2E), -ECLAMP, ECLAMP));
            hh = (1.0f - ec) * rcp4((eo + 1.0f) * (ec + 1.0f));    // sig(o)*tanh(c)

            // h store: truncation pack, 4x ds_write_b16
            short* hw = wb[(t + 1) & 1];
            hw[0 * HS] = (short)((fbits(hh.x) + 0x8000u) >> 16);
            hw[1 * HS] = (short)((fbits(hh.y) + 0x8000u) >> 16);
            hw[2 * HS] = (short)((fbits(hh.z) + 0x8000u) >> 16);
            hw[3 * HS] = (short)((fbits(hh.w) + 0x8000u) >> 16);
        }
    }

    // ---- epilogue: out[b0+r][o] = h_T[r] . W_fc[o] + b_fc[o]  (fp32 h)
    Hf[rbase + 0][jw] = hh.x;
    Hf[rbase + 1][jw] = hh.y;
    Hf[rbase + 2][jw] = hh.z;
    Hf[rbase + 3][jw] = hh.w;
    __syncthreads();

    if (tid < BR * O_SZ) {               // 128 threads
        const int r = tid >> 3;
        const int o = tid & 7;
        const float* wf = W_fc + o * H_SZ;
        float acc = b_fc[o];
        #pragma unroll
        for (int jx = 0; jx < H_SZ; ++jx) acc += Hf[r][jx] * wf[jx];
        out[(size_t)(b0 + r) * O_SZ + o] = acc;
    }
}

extern "C" void kernel_launch(void* const* d_in, const int* in_sizes, int n_in,
                              void* d_out, int out_size, void* d_ws, size_t ws_size,
                              hipStream_t stream) {
    const float* x    = (const float*)d_in[0];
    const float* W_ih = (const float*)d_in[1];
    const float* W_hh = (const float*)d_in[2];
    const float* b_ih = (const float*)d_in[3];
    const float* b_hh = (const float*)d_in[4];
    const float* W_fc = (const float*)d_in[5];
    const float* b_fc = (const float*)d_in[6];
    float* out = (float*)d_out;

    const int B = 4096;
    lstm_fused_kernel<<<dim3(B / BR), dim3(256), 0, stream>>>(
        x, W_ih, W_hh, b_ih, b_hh, W_fc, b_fc, out);
}